// Round 1
// baseline (185.037 us; speedup 1.0000x reference)
//
#include <hip/hip_runtime.h>
#include <stdint.h>

#define N_REAL 500
#define NPAD   512
#define K_IN   3072
#define NBATCH 8192
#define NOUT   10
#define RADIUS 20.0f
#define VOLF   100.0f

typedef __attribute__((ext_vector_type(8))) __bf16 bf16x8;
typedef __attribute__((ext_vector_type(4))) float  f32x4;
typedef __attribute__((ext_vector_type(4))) unsigned short us4;

__device__ __forceinline__ unsigned short f2bf(float f) {
    unsigned int u = __float_as_uint(f);
    u += 0x7FFFu + ((u >> 16) & 1u);           // round-to-nearest-even
    return (unsigned short)(u >> 16);
}
__device__ __forceinline__ float bf2f(unsigned short h) {
    return __uint_as_float(((unsigned int)h) << 16);
}

#define GLOBAL_AS __attribute__((address_space(1)))
#define LDS_AS    __attribute__((address_space(3)))
__device__ __forceinline__ void glds16(const void* g, void* l) {
    __builtin_amdgcn_global_load_lds((const GLOBAL_AS void*)g, (LDS_AS void*)l, 16, 0, 0);
}

// ---------------- prep1: per-neuron scalars + feature normalize ----------------
__global__ void prep1(const float* __restrict__ positions,
                      const float* __restrict__ features,
                      const float* __restrict__ out_w,
                      const float* __restrict__ biases,
                      float* __restrict__ feat_norm,   // [512][64]
                      float* __restrict__ pos_c,       // [512][4]
                      float* __restrict__ inw,         // [512]
                      float* __restrict__ biasp,       // [512]
                      float* __restrict__ wout)        // [512][10]
{
    int n = threadIdx.x;  // 512 threads, 1 block
    float e_in = 0.f, e_out = 0.f;
    float px = 0.f, py = 0.f, pz = 0.f;
    if (n < N_REAL) {
        px = fminf(fmaxf(positions[n*3+0], 0.1f), VOLF - 0.1f);
        py = fminf(fmaxf(positions[n*3+1], 0.1f), VOLF - 0.1f);
        pz = fminf(fmaxf(positions[n*3+2], 0.1f), VOLF - 0.1f);
        float xn = px / VOLF;
        e_in  = expf(-2.f * xn);
        e_out = expf(2.f * (xn - 1.f));
        float ss = 0.f;
        for (int f = 0; f < 64; ++f) { float v = features[n*64+f]; ss += v*v; }
        float nm = fmaxf(sqrtf(ss), 1e-6f);
        for (int f = 0; f < 64; ++f) feat_norm[n*64+f] = features[n*64+f] / nm;
    } else {
        for (int f = 0; f < 64; ++f) feat_norm[n*64+f] = 0.f;
    }
    pos_c[n*4+0] = px; pos_c[n*4+1] = py; pos_c[n*4+2] = pz; pos_c[n*4+3] = 0.f;

    __shared__ float s_in[512], s_out[512];
    s_in[n] = e_in; s_out[n] = e_out;
    __syncthreads();
    for (int s = 256; s > 0; s >>= 1) {
        if (n < s) { s_in[n] += s_in[n+s]; s_out[n] += s_out[n+s]; }
        __syncthreads();
    }
    float sum_in  = s_in[0]  + 1e-6f;
    float sum_out = s_out[0] + 1e-6f;

    inw[n]   = (n < N_REAL) ? (e_in / sum_in) : 0.f;
    biasp[n] = (n < N_REAL) ? biases[n] : 0.f;
    float wo = (n < N_REAL) ? (e_out / sum_out) : 0.f;
    for (int o = 0; o < NOUT; ++o)
        wout[n*NOUT + o] = (n < N_REAL) ? out_w[n*NOUT + o] * wo : 0.f;
}

// ---------------- prep2: connection weights (row i per block) ----------------
__global__ void prep2(const float* __restrict__ pos_c,
                      const float* __restrict__ feat_norm,
                      unsigned short* __restrict__ conn_w)   // [512][512] bf16
{
    int i = blockIdx.x;   // 512
    int t = threadIdx.x;  // 128
    __shared__ float fi[64];
    __shared__ float spos[4];
    __shared__ float red[128];
    if (t < 64) fi[t] = feat_norm[i*64 + t];
    if (t < 4)  spos[t] = pos_c[i*4 + t];
    __syncthreads();

    float w[4];
    float part = 0.f;
    for (int jj = 0; jj < 4; ++jj) {
        int j = t + jj*128;
        float val = 0.f;
        if (i < N_REAL && j < N_REAL) {
            float dx = spos[0] - pos_c[j*4+0];
            float dy = spos[1] - pos_c[j*4+1];
            float dz = spos[2] - pos_c[j*4+2];
            float sq = dx*dx + dy*dy + dz*dz;
            if (sq > 0.f) {
                float dist = sqrtf(sq);
                if (dist < RADIUS) {
                    float att = expf(-dist / RADIUS);
                    float sim = 0.f;
                    const float4* fj = (const float4*)(feat_norm + j*64);
                    const float4* fi4 = (const float4*)fi;
                    #pragma unroll
                    for (int f = 0; f < 16; ++f) {
                        float4 a = fi4[f]; float4 b = fj[f];
                        sim += a.x*b.x + a.y*b.y + a.z*b.z + a.w*b.w;
                    }
                    sim = fminf(fmaxf(sim, -1.f), 1.f);
                    val = att * (0.5f + 0.5f*sim);
                }
            }
        }
        w[jj] = val; part += val;
    }
    red[t] = part;
    __syncthreads();
    for (int s = 64; s > 0; s >>= 1) {
        if (t < s) red[t] += red[t+s];
        __syncthreads();
    }
    float inv = 1.f / (red[0] + 1e-6f);
    for (int jj = 0; jj < 4; ++jj)
        conn_w[(long)i*NPAD + t + jj*128] = f2bf(w[jj] * inv);
}

// ---------------- cast/pad f32 -> bf16 (quad granularity) ----------------
__global__ void cast_pad(const float* __restrict__ src, unsigned short* __restrict__ dst,
                         long total_q, long src_q)
{
    long i = (long)blockIdx.x * blockDim.x + threadIdx.x;
    long stride = (long)gridDim.x * blockDim.x;
    for (; i < total_q; i += stride) {
        us4 o;
        if (i < src_q) {
            float4 v = ((const float4*)src)[i];
            o[0] = f2bf(v.x); o[1] = f2bf(v.y); o[2] = f2bf(v.z); o[3] = f2bf(v.w);
        } else {
            o[0] = 0; o[1] = 0; o[2] = 0; o[3] = 0;
        }
        ((us4*)dst)[i] = o;
    }
}

// ---------------- bf16 NT GEMM: C[m][n] = sum_k A[m][k]*B[n][k], fused epilogue ----------------
// MODE 0: C = acc*inw[n] + biasp[n]           (input projection)
// MODE 1: C = min(max(actOld + 0.5*acc, 0), 50)  (message passing step)
template<int MODE>
__global__ __launch_bounds__(256)
void gemm_nt(const unsigned short* __restrict__ A,       // [M][K] bf16
             const unsigned short* __restrict__ B,       // [512][K] bf16
             unsigned short* __restrict__ Cbf,           // [M][512] bf16
             const unsigned short* __restrict__ actOld,  // MODE1: [M][512] bf16
             const float* __restrict__ inw,
             const float* __restrict__ biasp,
             int K)
{
    __shared__ unsigned short As[128*32];  // 8 KiB
    __shared__ unsigned short Bs[128*32];  // 8 KiB

    const int tid  = threadIdx.x;
    const int lane = tid & 63;
    const int wave = tid >> 6;
    const int m0 = blockIdx.x * 128;
    const int n0 = blockIdx.y * 128;
    const int wm = (wave >> 1) * 64;
    const int wn = (wave & 1) * 64;

    f32x4 acc[4][4];
    #pragma unroll
    for (int i = 0; i < 4; ++i)
        #pragma unroll
        for (int j = 0; j < 4; ++j)
            acc[i][j] = (f32x4){0.f, 0.f, 0.f, 0.f};

    // staging: two 4096B issues per tile, linear LDS layout [row][k] 64B/row
    const int o0 = tid * 16;
    const int o1 = o0 + 4096;
    const int r0 = o0 >> 6, c0 = o0 & 63;
    const int r1 = o1 >> 6, c1 = o1 & 63;
    const char* a0p = (const char*)A + ((long)(m0 + r0) * K) * 2 + c0;
    const char* a1p = (const char*)A + ((long)(m0 + r1) * K) * 2 + c1;
    const char* b0p = (const char*)B + ((long)(n0 + r0) * K) * 2 + c0;
    const char* b1p = (const char*)B + ((long)(n0 + r1) * K) * 2 + c1;
    char* lA0 = (char*)As + o0;  char* lA1 = (char*)As + o1;
    char* lB0 = (char*)Bs + o0;  char* lB1 = (char*)Bs + o1;

    const int mrow = wm + (lane & 15);
    const int nrow = wn + (lane & 15);
    const int kc   = (lane >> 4) * 8;

    for (int k0 = 0; k0 < K; k0 += 32) {
        __syncthreads();
        glds16(a0p, lA0);
        glds16(a1p, lA1);
        glds16(b0p, lB0);
        glds16(b1p, lB1);
        a0p += 64; a1p += 64; b0p += 64; b1p += 64;
        asm volatile("s_waitcnt vmcnt(0)" ::: "memory");
        __syncthreads();

        bf16x8 af[4], bfv[4];
        #pragma unroll
        for (int f = 0; f < 4; ++f) {
            af[f]  = *(const bf16x8*)(As + (mrow + f*16)*32 + kc);
            bfv[f] = *(const bf16x8*)(Bs + (nrow + f*16)*32 + kc);
        }
        #pragma unroll
        for (int i = 0; i < 4; ++i)
            #pragma unroll
            for (int j = 0; j < 4; ++j)
                acc[i][j] = __builtin_amdgcn_mfma_f32_16x16x32_bf16(af[i], bfv[j], acc[i][j], 0, 0, 0);
    }

    // epilogue: D lane mapping col = lane&15, row = (lane>>4)*4 + r
    const int mbase = m0 + wm + (lane >> 4) * 4;
    const int nbase = n0 + wn + (lane & 15);
    #pragma unroll
    for (int j = 0; j < 4; ++j) {
        const int n = nbase + j*16;
        float win = 0.f, bia = 0.f;
        if (MODE == 0) { win = inw[n]; bia = biasp[n]; }
        #pragma unroll
        for (int i = 0; i < 4; ++i) {
            #pragma unroll
            for (int r = 0; r < 4; ++r) {
                const long m = mbase + i*16 + r;
                float v = acc[i][j][r];
                if (MODE == 0) {
                    v = v * win + bia;
                } else {
                    float old = bf2f(actOld[m*NPAD + n]);
                    v = fminf(fmaxf(old + 0.5f*v, 0.f), 50.f);
                }
                Cbf[m*NPAD + n] = f2bf(v);
            }
        }
    }
}

// ---------------- final projection: out[8192][10] = act @ wout ----------------
__global__ __launch_bounds__(256)
void out_gemm(const unsigned short* __restrict__ act,  // [8192][512] bf16
              const float* __restrict__ wout,          // [512][10]
              float* __restrict__ out)                 // [8192][10]
{
    __shared__ float sw[NPAD * NOUT];
    const int tid = threadIdx.x;
    for (int i = tid; i < NPAD*NOUT; i += 256) sw[i] = wout[i];
    __syncthreads();

    const int lane = tid & 63;
    const int wv   = tid >> 6;
    const int row  = blockIdx.x * 4 + wv;

    const unsigned short* ap = act + (long)row * NPAD + lane * 8;
    us4 v0 = *(const us4*)(ap);
    us4 v1 = *(const us4*)(ap + 4);

    float p[NOUT];
    #pragma unroll
    for (int o = 0; o < NOUT; ++o) p[o] = 0.f;

    const int nb = lane * 8;
    #pragma unroll
    for (int e = 0; e < 8; ++e) {
        float a = bf2f(e < 4 ? v0[e] : v1[e-4]);
        const float* wr = &sw[(nb + e) * NOUT];
        #pragma unroll
        for (int o = 0; o < NOUT; ++o) p[o] += a * wr[o];
    }
    #pragma unroll
    for (int o = 0; o < NOUT; ++o) {
        float s = p[o];
        for (int d = 32; d > 0; d >>= 1) s += __shfl_down(s, d);
        if (lane == 0) out[(long)row * NOUT + o] = s;
    }
}

extern "C" void kernel_launch(void* const* d_in, const int* in_sizes, int n_in,
                              void* d_out, int out_size, void* d_ws, size_t ws_size,
                              hipStream_t stream)
{
    const float* x        = (const float*)d_in[0];
    const float* pos      = (const float*)d_in[1];
    const float* in_w     = (const float*)d_in[2];
    const float* feats    = (const float*)d_in[3];
    const float* out_w    = (const float*)d_in[4];
    const float* biases   = (const float*)d_in[5];
    float* out = (float*)d_out;

    char* ws = (char*)d_ws;
    unsigned short* x_bf   = (unsigned short*)(ws);                  // 50,331,648 B
    unsigned short* iw_bf  = (unsigned short*)(ws + 50331648);       //  3,145,728 B
    unsigned short* connw  = (unsigned short*)(ws + 53477376);       //    524,288 B
    unsigned short* act_a  = (unsigned short*)(ws + 54001664);       //  8,388,608 B
    unsigned short* act_b  = (unsigned short*)(ws + 62390272);       //  8,388,608 B
    float* feat_norm = (float*)(ws + 70778880);                      //    131,072 B
    float* pos_c     = (float*)(ws + 70909952);                      //      8,192 B
    float* inw       = (float*)(ws + 70918144);                      //      2,048 B
    float* biasp     = (float*)(ws + 70920192);                      //      2,048 B
    float* wout      = (float*)(ws + 70922240);                      //     20,480 B

    prep1<<<1, 512, 0, stream>>>(pos, feats, out_w, biases, feat_norm, pos_c, inw, biasp, wout);
    prep2<<<512, 128, 0, stream>>>(pos_c, feat_norm, connw);
    cast_pad<<<2048, 256, 0, stream>>>(x, x_bf, 6291456L, 6291456L);
    cast_pad<<<512, 256, 0, stream>>>(in_w, iw_bf, 393216L, 384000L);

    dim3 gdim(NBATCH/128, NPAD/128);
    gemm_nt<0><<<gdim, 256, 0, stream>>>(x_bf, iw_bf, act_a, nullptr, inw, biasp, K_IN);
    gemm_nt<1><<<gdim, 256, 0, stream>>>(act_a, connw, act_b, act_a, nullptr, nullptr, NPAD);
    gemm_nt<1><<<gdim, 256, 0, stream>>>(act_b, connw, act_a, act_b, nullptr, nullptr, NPAD);
    gemm_nt<1><<<gdim, 256, 0, stream>>>(act_a, connw, act_b, act_a, nullptr, nullptr, NPAD);

    out_gemm<<<NBATCH/4, 256, 0, stream>>>(act_b, wout, out);
}

// Round 2
// 133.404 us; speedup vs baseline: 1.3870x; 1.3870x over previous
//
#include <hip/hip_runtime.h>
#include <stdint.h>

#define N_REAL 500
#define NPAD   512
#define K_IN   3072
#define NBATCH 8192
#define NOUT   10
#define RADIUS 20.0f
#define VOLF   100.0f

typedef __attribute__((ext_vector_type(8))) __bf16 bf16x8;
typedef __attribute__((ext_vector_type(4))) float  f32x4;
typedef __attribute__((ext_vector_type(4))) unsigned short us4;

__device__ __forceinline__ unsigned short f2bf(float f) {
    unsigned int u = __float_as_uint(f);
    u += 0x7FFFu + ((u >> 16) & 1u);           // round-to-nearest-even
    return (unsigned short)(u >> 16);
}
__device__ __forceinline__ float bf2f(unsigned short h) {
    return __uint_as_float(((unsigned int)h) << 16);
}

#define GLOBAL_AS __attribute__((address_space(1)))
#define LDS_AS    __attribute__((address_space(3)))
__device__ __forceinline__ void glds16(const void* g, void* l) {
    __builtin_amdgcn_global_load_lds((const GLOBAL_AS void*)g, (LDS_AS void*)l, 16, 0, 0);
}

// ---------------- prep1: per-neuron scalars + feature normalize ----------------
__global__ void prep1(const float* __restrict__ positions,
                      const float* __restrict__ features,
                      const float* __restrict__ out_w,
                      const float* __restrict__ biases,
                      float* __restrict__ feat_norm,   // [512][64]
                      float* __restrict__ pos_c,       // [512][4]
                      float* __restrict__ inw,         // [512]
                      float* __restrict__ biasp,       // [512]
                      float* __restrict__ wout)        // [512][10]
{
    int n = threadIdx.x;  // 512 threads, 1 block
    float e_in = 0.f, e_out = 0.f;
    float px = 0.f, py = 0.f, pz = 0.f;
    if (n < N_REAL) {
        px = fminf(fmaxf(positions[n*3+0], 0.1f), VOLF - 0.1f);
        py = fminf(fmaxf(positions[n*3+1], 0.1f), VOLF - 0.1f);
        pz = fminf(fmaxf(positions[n*3+2], 0.1f), VOLF - 0.1f);
        float xn = px / VOLF;
        e_in  = expf(-2.f * xn);
        e_out = expf(2.f * (xn - 1.f));
        float ss = 0.f;
        for (int f = 0; f < 64; ++f) { float v = features[n*64+f]; ss += v*v; }
        float nm = fmaxf(sqrtf(ss), 1e-6f);
        for (int f = 0; f < 64; ++f) feat_norm[n*64+f] = features[n*64+f] / nm;
    } else {
        for (int f = 0; f < 64; ++f) feat_norm[n*64+f] = 0.f;
    }
    pos_c[n*4+0] = px; pos_c[n*4+1] = py; pos_c[n*4+2] = pz; pos_c[n*4+3] = 0.f;

    __shared__ float s_in[512], s_out[512];
    s_in[n] = e_in; s_out[n] = e_out;
    __syncthreads();
    for (int s = 256; s > 0; s >>= 1) {
        if (n < s) { s_in[n] += s_in[n+s]; s_out[n] += s_out[n+s]; }
        __syncthreads();
    }
    float sum_in  = s_in[0]  + 1e-6f;
    float sum_out = s_out[0] + 1e-6f;

    inw[n]   = (n < N_REAL) ? (e_in / sum_in) : 0.f;
    biasp[n] = (n < N_REAL) ? biases[n] : 0.f;
    float wo = (n < N_REAL) ? (e_out / sum_out) : 0.f;
    for (int o = 0; o < NOUT; ++o)
        wout[n*NOUT + o] = (n < N_REAL) ? out_w[n*NOUT + o] * wo : 0.f;
}

// ---------------- prep2: connection weights (row i per block) ----------------
__global__ void prep2(const float* __restrict__ pos_c,
                      const float* __restrict__ feat_norm,
                      unsigned short* __restrict__ conn_w)   // [512][512] bf16
{
    int i = blockIdx.x;   // 512
    int t = threadIdx.x;  // 128
    __shared__ float fi[64];
    __shared__ float spos[4];
    __shared__ float red[128];
    if (t < 64) fi[t] = feat_norm[i*64 + t];
    if (t < 4)  spos[t] = pos_c[i*4 + t];
    __syncthreads();

    float w[4];
    float part = 0.f;
    for (int jj = 0; jj < 4; ++jj) {
        int j = t + jj*128;
        float val = 0.f;
        if (i < N_REAL && j < N_REAL) {
            float dx = spos[0] - pos_c[j*4+0];
            float dy = spos[1] - pos_c[j*4+1];
            float dz = spos[2] - pos_c[j*4+2];
            float sq = dx*dx + dy*dy + dz*dz;
            if (sq > 0.f) {
                float dist = sqrtf(sq);
                if (dist < RADIUS) {
                    float att = expf(-dist / RADIUS);
                    float sim = 0.f;
                    const float4* fj = (const float4*)(feat_norm + j*64);
                    const float4* fi4 = (const float4*)fi;
                    #pragma unroll
                    for (int f = 0; f < 16; ++f) {
                        float4 a = fi4[f]; float4 b = fj[f];
                        sim += a.x*b.x + a.y*b.y + a.z*b.z + a.w*b.w;
                    }
                    sim = fminf(fmaxf(sim, -1.f), 1.f);
                    val = att * (0.5f + 0.5f*sim);
                }
            }
        }
        w[jj] = val; part += val;
    }
    red[t] = part;
    __syncthreads();
    for (int s = 64; s > 0; s >>= 1) {
        if (t < s) red[t] += red[t+s];
        __syncthreads();
    }
    float inv = 1.f / (red[0] + 1e-6f);
    for (int jj = 0; jj < 4; ++jj)
        conn_w[(long)i*NPAD + t + jj*128] = f2bf(w[jj] * inv);
}

// ---------------- cast/pad f32 -> bf16 (quad granularity) ----------------
__global__ void cast_pad(const float* __restrict__ src, unsigned short* __restrict__ dst,
                         long total_q, long src_q)
{
    long i = (long)blockIdx.x * blockDim.x + threadIdx.x;
    long stride = (long)gridDim.x * blockDim.x;
    for (; i < total_q; i += stride) {
        us4 o;
        if (i < src_q) {
            float4 v = ((const float4*)src)[i];
            o[0] = f2bf(v.x); o[1] = f2bf(v.y); o[2] = f2bf(v.z); o[3] = f2bf(v.w);
        } else {
            o[0] = 0; o[1] = 0; o[2] = 0; o[3] = 0;
        }
        ((us4*)dst)[i] = o;
    }
}

// XCD-grouped block mapping: 512 blocks = 64 mb x 8 nb; each XCD owns 8 mb,
// iterates nb fastest so the A row-panel stays hot in that XCD's L2.
__device__ __forceinline__ void block_map(int b, int& m0, int& n0) {
    int xcd = b & 7, loc = b >> 3;
    m0 = (xcd*8 + (loc >> 3)) * 128;
    n0 = (loc & 7) * 64;
}

// ---------------- GEMM1: act = (x @ iw^T) * inw + bias, fused f32->bf16 cast ----------------
// Tile 128x64, BK=64, 4 waves (2x2, each 64x32). LDS XOR-swizzle (row&7)<<4.
__global__ __launch_bounds__(256)
void gemm1(const float* __restrict__ X,            // [8192][3072] f32
           const unsigned short* __restrict__ B,   // [512][3072] bf16
           unsigned short* __restrict__ Cbf,       // [8192][512] bf16
           const float* __restrict__ inw,
           const float* __restrict__ biasp)
{
    __shared__ unsigned short As[128*64];  // 16 KiB, swizzled
    __shared__ unsigned short Bs[64*64];   //  8 KiB, swizzled

    const int tid  = threadIdx.x;
    const int lane = tid & 63;
    const int wave = tid >> 6;
    int m0, n0; block_map(blockIdx.x, m0, n0);
    const int wm = (wave >> 1) * 64;
    const int wn = (wave & 1) * 32;

    f32x4 acc[4][2];
    #pragma unroll
    for (int i = 0; i < 4; ++i)
        #pragma unroll
        for (int j = 0; j < 2; ++j)
            acc[i][j] = (f32x4){0.f,0.f,0.f,0.f};

    // A reg-staging: 128 rows x 16 float4 = 2048 f4, 8 per thread
    const float4* gA[8]; unsigned short* lA[8];
    #pragma unroll
    for (int s = 0; s < 8; ++s) {
        int f = tid + s*256;
        int row = f >> 4, c4 = f & 15;
        gA[s] = (const float4*)(X + (long)(m0 + row) * K_IN) + c4;
        lA[s] = (unsigned short*)((char*)As + row*128 + ((c4*8) ^ ((row & 7) << 4)));
    }
    // B: 2 glds16 issues, pre-swizzled global source
    const char* gB[2]; char* lB[2];
    #pragma unroll
    for (int s = 0; s < 2; ++s) {
        int o = tid*16 + s*4096;
        int row = o >> 7, d = o & 127;
        gB[s] = (const char*)B + (long)(n0 + row) * (K_IN*2) + (d ^ ((row & 7) << 4));
        lB[s] = (char*)Bs + o;
    }

    for (int k0 = 0; k0 < K_IN; k0 += 64) {
        __syncthreads();
        glds16(gB[0], lB[0]);
        glds16(gB[1], lB[1]);
        gB[0] += 128; gB[1] += 128;
        float4 v[8];
        #pragma unroll
        for (int s = 0; s < 8; ++s) v[s] = gA[s][0];
        #pragma unroll
        for (int s = 0; s < 8; ++s) {
            us4 o;
            o[0] = f2bf(v[s].x); o[1] = f2bf(v[s].y);
            o[2] = f2bf(v[s].z); o[3] = f2bf(v[s].w);
            *(us4*)lA[s] = o;
            gA[s] += 16;  // advance 64 floats
        }
        asm volatile("s_waitcnt vmcnt(0) lgkmcnt(0)" ::: "memory");
        __syncthreads();

        #pragma unroll
        for (int kk = 0; kk < 2; ++kk) {
            const int cb = kk*64 + (lane >> 4) * 16;
            bf16x8 af[4], bfv[2];
            #pragma unroll
            for (int i = 0; i < 4; ++i) {
                int r = wm + i*16 + (lane & 15);
                af[i] = *(const bf16x8*)((const char*)As + r*128 + (cb ^ ((r & 7) << 4)));
            }
            #pragma unroll
            for (int j = 0; j < 2; ++j) {
                int r = wn + j*16 + (lane & 15);
                bfv[j] = *(const bf16x8*)((const char*)Bs + r*128 + (cb ^ ((r & 7) << 4)));
            }
            #pragma unroll
            for (int i = 0; i < 4; ++i)
                #pragma unroll
                for (int j = 0; j < 2; ++j)
                    acc[i][j] = __builtin_amdgcn_mfma_f32_16x16x32_bf16(af[i], bfv[j], acc[i][j], 0, 0, 0);
        }
    }

    const int mbase = m0 + wm + (lane >> 4) * 4;
    const int nbase = n0 + wn + (lane & 15);
    #pragma unroll
    for (int j = 0; j < 2; ++j) {
        const int n = nbase + j*16;
        const float win = inw[n], bia = biasp[n];
        #pragma unroll
        for (int i = 0; i < 4; ++i)
            #pragma unroll
            for (int r = 0; r < 4; ++r) {
                const long m = mbase + i*16 + r;
                Cbf[m*NPAD + n] = f2bf(acc[i][j][r] * win + bia);
            }
    }
}

// ---------------- GEMM2: act' = min(relu(act + 0.5 * act @ connw^T), 50) ----------------
__global__ __launch_bounds__(256)
void gemm2(const unsigned short* __restrict__ A,      // act [8192][512] bf16
           const unsigned short* __restrict__ B,      // connw [512][512] bf16
           unsigned short* __restrict__ Cbf,          // [8192][512] bf16
           const unsigned short* __restrict__ actOld) // == A
{
    __shared__ unsigned short As[128*64];
    __shared__ unsigned short Bs[64*64];

    const int tid  = threadIdx.x;
    const int lane = tid & 63;
    const int wave = tid >> 6;
    int m0, n0; block_map(blockIdx.x, m0, n0);
    const int wm = (wave >> 1) * 64;
    const int wn = (wave & 1) * 32;

    f32x4 acc[4][2];
    #pragma unroll
    for (int i = 0; i < 4; ++i)
        #pragma unroll
        for (int j = 0; j < 2; ++j)
            acc[i][j] = (f32x4){0.f,0.f,0.f,0.f};

    // A: 4 glds16, B: 2 glds16, both pre-swizzled source
    const char* gA[4]; char* lA[4];
    #pragma unroll
    for (int s = 0; s < 4; ++s) {
        int o = tid*16 + s*4096;
        int row = o >> 7, d = o & 127;
        gA[s] = (const char*)A + (long)(m0 + row) * (NPAD*2) + (d ^ ((row & 7) << 4));
        lA[s] = (char*)As + o;
    }
    const char* gB[2]; char* lB[2];
    #pragma unroll
    for (int s = 0; s < 2; ++s) {
        int o = tid*16 + s*4096;
        int row = o >> 7, d = o & 127;
        gB[s] = (const char*)B + (long)(n0 + row) * (NPAD*2) + (d ^ ((row & 7) << 4));
        lB[s] = (char*)Bs + o;
    }

    for (int k0 = 0; k0 < NPAD; k0 += 64) {
        __syncthreads();
        #pragma unroll
        for (int s = 0; s < 4; ++s) { glds16(gA[s], lA[s]); gA[s] += 128; }
        #pragma unroll
        for (int s = 0; s < 2; ++s) { glds16(gB[s], lB[s]); gB[s] += 128; }
        asm volatile("s_waitcnt vmcnt(0)" ::: "memory");
        __syncthreads();

        #pragma unroll
        for (int kk = 0; kk < 2; ++kk) {
            const int cb = kk*64 + (lane >> 4) * 16;
            bf16x8 af[4], bfv[2];
            #pragma unroll
            for (int i = 0; i < 4; ++i) {
                int r = wm + i*16 + (lane & 15);
                af[i] = *(const bf16x8*)((const char*)As + r*128 + (cb ^ ((r & 7) << 4)));
            }
            #pragma unroll
            for (int j = 0; j < 2; ++j) {
                int r = wn + j*16 + (lane & 15);
                bfv[j] = *(const bf16x8*)((const char*)Bs + r*128 + (cb ^ ((r & 7) << 4)));
            }
            #pragma unroll
            for (int i = 0; i < 4; ++i)
                #pragma unroll
                for (int j = 0; j < 2; ++j)
                    acc[i][j] = __builtin_amdgcn_mfma_f32_16x16x32_bf16(af[i], bfv[j], acc[i][j], 0, 0, 0);
        }
    }

    const int mbase = m0 + wm + (lane >> 4) * 4;
    const int nbase = n0 + wn + (lane & 15);
    #pragma unroll
    for (int j = 0; j < 2; ++j) {
        const int n = nbase + j*16;
        #pragma unroll
        for (int i = 0; i < 4; ++i)
            #pragma unroll
            for (int r = 0; r < 4; ++r) {
                const long m = mbase + i*16 + r;
                float old = bf2f(actOld[m*NPAD + n]);
                float vv = fminf(fmaxf(old + 0.5f * acc[i][j][r], 0.f), 50.f);
                Cbf[m*NPAD + n] = f2bf(vv);
            }
    }
}

// ---------------- final projection: out[8192][10] = act @ wout ----------------
__global__ __launch_bounds__(256)
void out_gemm(const unsigned short* __restrict__ act,  // [8192][512] bf16
              const float* __restrict__ wout,          // [512][10]
              float* __restrict__ out)                 // [8192][10]
{
    __shared__ float sw[NPAD * NOUT];
    const int tid = threadIdx.x;
    for (int i = tid; i < NPAD*NOUT; i += 256) sw[i] = wout[i];
    __syncthreads();

    const int lane = tid & 63;
    const int wv   = tid >> 6;
    const int row  = blockIdx.x * 4 + wv;

    const unsigned short* ap = act + (long)row * NPAD + lane * 8;
    us4 v0 = *(const us4*)(ap);
    us4 v1 = *(const us4*)(ap + 4);

    float p[NOUT];
    #pragma unroll
    for (int o = 0; o < NOUT; ++o) p[o] = 0.f;

    const int nb = lane * 8;
    #pragma unroll
    for (int e = 0; e < 8; ++e) {
        float a = bf2f(e < 4 ? v0[e] : v1[e-4]);
        const float* wr = &sw[(nb + e) * NOUT];
        #pragma unroll
        for (int o = 0; o < NOUT; ++o) p[o] += a * wr[o];
    }
    #pragma unroll
    for (int o = 0; o < NOUT; ++o) {
        float s = p[o];
        for (int d = 32; d > 0; d >>= 1) s += __shfl_down(s, d);
        if (lane == 0) out[(long)row * NOUT + o] = s;
    }
}

extern "C" void kernel_launch(void* const* d_in, const int* in_sizes, int n_in,
                              void* d_out, int out_size, void* d_ws, size_t ws_size,
                              hipStream_t stream)
{
    const float* x        = (const float*)d_in[0];
    const float* pos      = (const float*)d_in[1];
    const float* in_w     = (const float*)d_in[2];
    const float* feats    = (const float*)d_in[3];
    const float* out_w    = (const float*)d_in[4];
    const float* biases   = (const float*)d_in[5];
    float* out = (float*)d_out;

    char* ws = (char*)d_ws;
    unsigned short* iw_bf  = (unsigned short*)(ws);                  //  3,145,728 B
    unsigned short* connw  = (unsigned short*)(ws + 3145728);        //    524,288 B
    unsigned short* act_a  = (unsigned short*)(ws + 3670016);        //  8,388,608 B
    unsigned short* act_b  = (unsigned short*)(ws + 12058624);       //  8,388,608 B
    float* feat_norm = (float*)(ws + 20447232);                      //    131,072 B
    float* pos_c     = (float*)(ws + 20578304);                      //      8,192 B
    float* inw       = (float*)(ws + 20586496);                      //      2,048 B
    float* biasp     = (float*)(ws + 20588544);                      //      2,048 B
    float* wout      = (float*)(ws + 20590592);                      //     20,480 B

    prep1<<<1, 512, 0, stream>>>(pos, feats, out_w, biases, feat_norm, pos_c, inw, biasp, wout);
    prep2<<<512, 128, 0, stream>>>(pos_c, feat_norm, connw);
    cast_pad<<<512, 256, 0, stream>>>(in_w, iw_bf, 393216L, 384000L);

    gemm1<<<512, 256, 0, stream>>>(x, iw_bf, act_a, inw, biasp);
    gemm2<<<512, 256, 0, stream>>>(act_a, connw, act_b, act_a);
    gemm2<<<512, 256, 0, stream>>>(act_b, connw, act_a, act_b);
    gemm2<<<512, 256, 0, stream>>>(act_a, connw, act_b, act_a);

    out_gemm<<<NBATCH/4, 256, 0, stream>>>(act_b, wout, out);
}

// Round 3
// 130.717 us; speedup vs baseline: 1.4155x; 1.0206x over previous
//
#include <hip/hip_runtime.h>
#include <stdint.h>

#define N_REAL 500
#define NPAD   512
#define K_IN   3072
#define NBATCH 8192
#define NOUT   10
#define RADIUS 20.0f
#define VOLF   100.0f

typedef __attribute__((ext_vector_type(8))) __bf16 bf16x8;
typedef __attribute__((ext_vector_type(4))) float  f32x4;
typedef __attribute__((ext_vector_type(4))) unsigned short us4;

__device__ __forceinline__ unsigned short f2bf(float f) {
    unsigned int u = __float_as_uint(f);
    u += 0x7FFFu + ((u >> 16) & 1u);           // round-to-nearest-even
    return (unsigned short)(u >> 16);
}
__device__ __forceinline__ float bf2f(unsigned short h) {
    return __uint_as_float(((unsigned int)h) << 16);
}
// HW packed f32->bf16 (RNE), 2 insts per float4  [T12 recipe, gfx950-verified]
__device__ __forceinline__ uint2 cvt_pk4(float4 v) {
    uint2 r;
    asm("v_cvt_pk_bf16_f32 %0, %1, %2" : "=v"(r.x) : "v"(v.x), "v"(v.y));
    asm("v_cvt_pk_bf16_f32 %0, %1, %2" : "=v"(r.y) : "v"(v.z), "v"(v.w));
    return r;
}

#define GLOBAL_AS __attribute__((address_space(1)))
#define LDS_AS    __attribute__((address_space(3)))
__device__ __forceinline__ void glds16(const void* g, void* l) {
    __builtin_amdgcn_global_load_lds((const GLOBAL_AS void*)g, (LDS_AS void*)l, 16, 0, 0);
}

// ---------------- prep1 ----------------
__global__ void prep1(const float* __restrict__ positions,
                      const float* __restrict__ features,
                      const float* __restrict__ out_w,
                      const float* __restrict__ biases,
                      float* __restrict__ feat_norm,   // [512][64]
                      float* __restrict__ pos_c,       // [512][4]
                      float* __restrict__ inw,         // [512]
                      float* __restrict__ biasp,       // [512]
                      float* __restrict__ wout)        // [512][10]
{
    int n = threadIdx.x;  // 512 threads, 1 block
    float e_in = 0.f, e_out = 0.f;
    float px = 0.f, py = 0.f, pz = 0.f;
    if (n < N_REAL) {
        px = fminf(fmaxf(positions[n*3+0], 0.1f), VOLF - 0.1f);
        py = fminf(fmaxf(positions[n*3+1], 0.1f), VOLF - 0.1f);
        pz = fminf(fmaxf(positions[n*3+2], 0.1f), VOLF - 0.1f);
        float xn = px / VOLF;
        e_in  = expf(-2.f * xn);
        e_out = expf(2.f * (xn - 1.f));
        float ss = 0.f;
        for (int f = 0; f < 64; ++f) { float v = features[n*64+f]; ss += v*v; }
        float nm = fmaxf(sqrtf(ss), 1e-6f);
        for (int f = 0; f < 64; ++f) feat_norm[n*64+f] = features[n*64+f] / nm;
    } else {
        for (int f = 0; f < 64; ++f) feat_norm[n*64+f] = 0.f;
    }
    pos_c[n*4+0] = px; pos_c[n*4+1] = py; pos_c[n*4+2] = pz; pos_c[n*4+3] = 0.f;

    __shared__ float s_in[512], s_out[512];
    s_in[n] = e_in; s_out[n] = e_out;
    __syncthreads();
    for (int s = 256; s > 0; s >>= 1) {
        if (n < s) { s_in[n] += s_in[n+s]; s_out[n] += s_out[n+s]; }
        __syncthreads();
    }
    float sum_in  = s_in[0]  + 1e-6f;
    float sum_out = s_out[0] + 1e-6f;

    inw[n]   = (n < N_REAL) ? (e_in / sum_in) : 0.f;
    biasp[n] = (n < N_REAL) ? biases[n] : 0.f;
    float wo = (n < N_REAL) ? (e_out / sum_out) : 0.f;
    for (int o = 0; o < NOUT; ++o)
        wout[n*NOUT + o] = (n < N_REAL) ? out_w[n*NOUT + o] * wo : 0.f;
}

// ---------------- prep2 ----------------
__global__ void prep2(const float* __restrict__ pos_c,
                      const float* __restrict__ feat_norm,
                      unsigned short* __restrict__ conn_w)   // [512][512] bf16
{
    int i = blockIdx.x;   // 512
    int t = threadIdx.x;  // 128
    __shared__ float fi[64];
    __shared__ float spos[4];
    __shared__ float red[128];
    if (t < 64) fi[t] = feat_norm[i*64 + t];
    if (t < 4)  spos[t] = pos_c[i*4 + t];
    __syncthreads();

    float w[4];
    float part = 0.f;
    for (int jj = 0; jj < 4; ++jj) {
        int j = t + jj*128;
        float val = 0.f;
        if (i < N_REAL && j < N_REAL) {
            float dx = spos[0] - pos_c[j*4+0];
            float dy = spos[1] - pos_c[j*4+1];
            float dz = spos[2] - pos_c[j*4+2];
            float sq = dx*dx + dy*dy + dz*dz;
            if (sq > 0.f) {
                float dist = sqrtf(sq);
                if (dist < RADIUS) {
                    float att = expf(-dist / RADIUS);
                    float sim = 0.f;
                    const float4* fj = (const float4*)(feat_norm + j*64);
                    const float4* fi4 = (const float4*)fi;
                    #pragma unroll
                    for (int f = 0; f < 16; ++f) {
                        float4 a = fi4[f]; float4 b = fj[f];
                        sim += a.x*b.x + a.y*b.y + a.z*b.z + a.w*b.w;
                    }
                    sim = fminf(fmaxf(sim, -1.f), 1.f);
                    val = att * (0.5f + 0.5f*sim);
                }
            }
        }
        w[jj] = val; part += val;
    }
    red[t] = part;
    __syncthreads();
    for (int s = 64; s > 0; s >>= 1) {
        if (t < s) red[t] += red[t+s];
        __syncthreads();
    }
    float inv = 1.f / (red[0] + 1e-6f);
    for (int jj = 0; jj < 4; ++jj)
        conn_w[(long)i*NPAD + t + jj*128] = f2bf(w[jj] * inv);
}

// ---------------- cast/pad f32 -> bf16 ----------------
__global__ void cast_pad(const float* __restrict__ src, unsigned short* __restrict__ dst,
                         long total_q, long src_q)
{
    long i = (long)blockIdx.x * blockDim.x + threadIdx.x;
    long stride = (long)gridDim.x * blockDim.x;
    for (; i < total_q; i += stride) {
        us4 o;
        if (i < src_q) {
            float4 v = ((const float4*)src)[i];
            o[0] = f2bf(v.x); o[1] = f2bf(v.y); o[2] = f2bf(v.z); o[3] = f2bf(v.w);
        } else {
            o[0] = 0; o[1] = 0; o[2] = 0; o[3] = 0;
        }
        ((us4*)dst)[i] = o;
    }
}

// XCD-grouped block mapping: 512 blocks = 64 mb x 8 nb; each XCD owns 8 mb,
// nb fastest so the A row-panel stays hot in that XCD's L2.
__device__ __forceinline__ void block_map(int b, int& m0, int& n0) {
    int xcd = b & 7, loc = b >> 3;
    m0 = (xcd*8 + (loc >> 3)) * 128;
    n0 = (loc & 7) * 64;
}

// ---------------- GEMM1: act = (x @ iw^T) * inw + bias, fused cast, dbuf pipeline ----------------
__global__ __launch_bounds__(256)
void gemm1(const float* __restrict__ X,            // [8192][3072] f32
           const unsigned short* __restrict__ B,   // [512][3072] bf16
           unsigned short* __restrict__ Cbf,       // [8192][512] bf16
           const float* __restrict__ inw,
           const float* __restrict__ biasp)
{
    __shared__ unsigned short As[2][128*64];  // 2 x 16 KiB, swizzled
    __shared__ unsigned short Bs[2][64*64];   // 2 x  8 KiB, swizzled

    const int tid  = threadIdx.x;
    const int lane = tid & 63;
    const int wave = tid >> 6;
    int m0, n0; block_map(blockIdx.x, m0, n0);
    const int wm = (wave >> 1) * 64;
    const int wn = (wave & 1) * 32;

    f32x4 acc[4][2];
    #pragma unroll
    for (int i = 0; i < 4; ++i)
        #pragma unroll
        for (int j = 0; j < 2; ++j)
            acc[i][j] = (f32x4){0.f,0.f,0.f,0.f};

    // A reg-staging: 128 rows x 16 float4, 8 per thread
    const float4* gA[8]; int lAo[8];
    #pragma unroll
    for (int s = 0; s < 8; ++s) {
        int f = tid + s*256;
        int row = f >> 4, c4 = f & 15;
        gA[s] = (const float4*)(X + (long)(m0 + row) * K_IN) + c4;
        lAo[s] = row*128 + ((c4*8) ^ ((row & 7) << 4));
    }
    // B: 2 glds16 issues, pre-swizzled global source
    const char* gB[2]; int lBo[2];
    #pragma unroll
    for (int s = 0; s < 2; ++s) {
        int o = tid*16 + s*4096;
        int row = o >> 7, d = o & 127;
        gB[s] = (const char*)B + (long)(n0 + row) * (K_IN*2) + (d ^ ((row & 7) << 4));
        lBo[s] = o;
    }

    // prologue: stage tile 0 into buf 0
    glds16(gB[0], (char*)Bs[0] + lBo[0]);
    glds16(gB[1], (char*)Bs[0] + lBo[1]);
    gB[0] += 128; gB[1] += 128;
    float4 v[8];
    #pragma unroll
    for (int s = 0; s < 8; ++s) { v[s] = gA[s][0]; gA[s] += 16; }
    #pragma unroll
    for (int s = 0; s < 8; ++s)
        *(uint2*)((char*)As[0] + lAo[s]) = cvt_pk4(v[s]);
    __syncthreads();

    for (int t = 0; t < 48; ++t) {
        const int cur = t & 1, nxt = cur ^ 1;
        const bool more = (t < 47);
        if (more) {
            glds16(gB[0], (char*)Bs[nxt] + lBo[0]);
            glds16(gB[1], (char*)Bs[nxt] + lBo[1]);
            gB[0] += 128; gB[1] += 128;
            #pragma unroll
            for (int s = 0; s < 8; ++s) { v[s] = gA[s][0]; gA[s] += 16; }
        }
        #pragma unroll
        for (int kk = 0; kk < 2; ++kk) {
            const int cb = kk*64 + (lane >> 4) * 16;
            bf16x8 afr[4], bfr[2];
            #pragma unroll
            for (int i = 0; i < 4; ++i) {
                int r = wm + i*16 + (lane & 15);
                afr[i] = *(const bf16x8*)((const char*)As[cur] + r*128 + (cb ^ ((r & 7) << 4)));
            }
            #pragma unroll
            for (int j = 0; j < 2; ++j) {
                int r = wn + j*16 + (lane & 15);
                bfr[j] = *(const bf16x8*)((const char*)Bs[cur] + r*128 + (cb ^ ((r & 7) << 4)));
            }
            #pragma unroll
            for (int i = 0; i < 4; ++i)
                #pragma unroll
                for (int j = 0; j < 2; ++j)
                    acc[i][j] = __builtin_amdgcn_mfma_f32_16x16x32_bf16(afr[i], bfr[j], acc[i][j], 0, 0, 0);
        }
        if (more) {
            #pragma unroll
            for (int s = 0; s < 8; ++s)
                *(uint2*)((char*)As[nxt] + lAo[s]) = cvt_pk4(v[s]);
        }
        __syncthreads();
    }

    const int mbase = m0 + wm + (lane >> 4) * 4;
    const int nbase = n0 + wn + (lane & 15);
    #pragma unroll
    for (int j = 0; j < 2; ++j) {
        const int n = nbase + j*16;
        const float win = inw[n], bia = biasp[n];
        #pragma unroll
        for (int i = 0; i < 4; ++i)
            #pragma unroll
            for (int r = 0; r < 4; ++r) {
                const long m = mbase + i*16 + r;
                Cbf[m*NPAD + n] = f2bf(acc[i][j][r] * win + bia);
            }
    }
}

// ---------------- GEMM2: act' = min(relu(act + 0.5 * act @ connw^T), 50), dbuf pipeline ----------------
__global__ __launch_bounds__(256)
void gemm2(const unsigned short* __restrict__ A,      // act [8192][512] bf16
           const unsigned short* __restrict__ B,      // connw [512][512] bf16
           unsigned short* __restrict__ Cbf,          // [8192][512] bf16
           const unsigned short* __restrict__ actOld) // == A
{
    __shared__ unsigned short As[2][128*64];
    __shared__ unsigned short Bs[2][64*64];

    const int tid  = threadIdx.x;
    const int lane = tid & 63;
    const int wave = tid >> 6;
    int m0, n0; block_map(blockIdx.x, m0, n0);
    const int wm = (wave >> 1) * 64;
    const int wn = (wave & 1) * 32;

    f32x4 acc[4][2];
    #pragma unroll
    for (int i = 0; i < 4; ++i)
        #pragma unroll
        for (int j = 0; j < 2; ++j)
            acc[i][j] = (f32x4){0.f,0.f,0.f,0.f};

    const char* gA[4]; int lAo[4];
    #pragma unroll
    for (int s = 0; s < 4; ++s) {
        int o = tid*16 + s*4096;
        int row = o >> 7, d = o & 127;
        gA[s] = (const char*)A + (long)(m0 + row) * (NPAD*2) + (d ^ ((row & 7) << 4));
        lAo[s] = o;
    }
    const char* gB[2]; int lBo[2];
    #pragma unroll
    for (int s = 0; s < 2; ++s) {
        int o = tid*16 + s*4096;
        int row = o >> 7, d = o & 127;
        gB[s] = (const char*)B + (long)(n0 + row) * (NPAD*2) + (d ^ ((row & 7) << 4));
        lBo[s] = o;
    }

    // prologue: stage tile 0 into buf 0
    #pragma unroll
    for (int s = 0; s < 4; ++s) { glds16(gA[s], (char*)As[0] + lAo[s]); gA[s] += 128; }
    #pragma unroll
    for (int s = 0; s < 2; ++s) { glds16(gB[s], (char*)Bs[0] + lBo[s]); gB[s] += 128; }

    // pre-issue epilogue actOld loads (hidden under K-loop)
    const int mbase = m0 + wm + (lane >> 4) * 4;
    const int nbase = n0 + wn + (lane & 15);
    unsigned short oldv[2][16];
    #pragma unroll
    for (int j = 0; j < 2; ++j)
        #pragma unroll
        for (int i = 0; i < 4; ++i)
            #pragma unroll
            for (int r = 0; r < 4; ++r)
                oldv[j][i*4+r] = actOld[(long)(mbase + i*16 + r)*NPAD + nbase + j*16];
    __syncthreads();

    for (int t = 0; t < 8; ++t) {
        const int cur = t & 1, nxt = cur ^ 1;
        const bool more = (t < 7);
        if (more) {
            #pragma unroll
            for (int s = 0; s < 4; ++s) { glds16(gA[s], (char*)As[nxt] + lAo[s]); gA[s] += 128; }
            #pragma unroll
            for (int s = 0; s < 2; ++s) { glds16(gB[s], (char*)Bs[nxt] + lBo[s]); gB[s] += 128; }
        }
        #pragma unroll
        for (int kk = 0; kk < 2; ++kk) {
            const int cb = kk*64 + (lane >> 4) * 16;
            bf16x8 afr[4], bfr[2];
            #pragma unroll
            for (int i = 0; i < 4; ++i) {
                int r = wm + i*16 + (lane & 15);
                afr[i] = *(const bf16x8*)((const char*)As[cur] + r*128 + (cb ^ ((r & 7) << 4)));
            }
            #pragma unroll
            for (int j = 0; j < 2; ++j) {
                int r = wn + j*16 + (lane & 15);
                bfr[j] = *(const bf16x8*)((const char*)Bs[cur] + r*128 + (cb ^ ((r & 7) << 4)));
            }
            #pragma unroll
            for (int i = 0; i < 4; ++i)
                #pragma unroll
                for (int j = 0; j < 2; ++j)
                    acc[i][j] = __builtin_amdgcn_mfma_f32_16x16x32_bf16(afr[i], bfr[j], acc[i][j], 0, 0, 0);
        }
        __syncthreads();
    }

    #pragma unroll
    for (int j = 0; j < 2; ++j) {
        const int n = nbase + j*16;
        #pragma unroll
        for (int i = 0; i < 4; ++i)
            #pragma unroll
            for (int r = 0; r < 4; ++r) {
                const long m = mbase + i*16 + r;
                float old = bf2f(oldv[j][i*4+r]);
                float vv = fminf(fmaxf(old + 0.5f * acc[i][j][r], 0.f), 50.f);
                Cbf[m*NPAD + n] = f2bf(vv);
            }
    }
}

// ---------------- final projection: out[8192][10] = act @ wout ----------------
__global__ __launch_bounds__(256)
void out_gemm(const unsigned short* __restrict__ act,  // [8192][512] bf16
              const float* __restrict__ wout,          // [512][10]
              float* __restrict__ out)                 // [8192][10]
{
    __shared__ float sw[NPAD * NOUT];
    const int tid = threadIdx.x;
    for (int i = tid; i < NPAD*NOUT; i += 256) sw[i] = wout[i];
    __syncthreads();

    const int lane = tid & 63;
    const int wv   = tid >> 6;
    const int row  = blockIdx.x * 4 + wv;

    const unsigned short* ap = act + (long)row * NPAD + lane * 8;
    us4 v0 = *(const us4*)(ap);
    us4 v1 = *(const us4*)(ap + 4);

    float p[NOUT];
    #pragma unroll
    for (int o = 0; o < NOUT; ++o) p[o] = 0.f;

    const int nb = lane * 8;
    #pragma unroll
    for (int e = 0; e < 8; ++e) {
        float a = bf2f(e < 4 ? v0[e] : v1[e-4]);
        const float* wr = &sw[(nb + e) * NOUT];
        #pragma unroll
        for (int o = 0; o < NOUT; ++o) p[o] += a * wr[o];
    }
    #pragma unroll
    for (int o = 0; o < NOUT; ++o) {
        float s = p[o];
        for (int d = 32; d > 0; d >>= 1) s += __shfl_down(s, d);
        if (lane == 0) out[(long)row * NOUT + o] = s;
    }
}

extern "C" void kernel_launch(void* const* d_in, const int* in_sizes, int n_in,
                              void* d_out, int out_size, void* d_ws, size_t ws_size,
                              hipStream_t stream)
{
    const float* x        = (const float*)d_in[0];
    const float* pos      = (const float*)d_in[1];
    const float* in_w     = (const float*)d_in[2];
    const float* feats    = (const float*)d_in[3];
    const float* out_w    = (const float*)d_in[4];
    const float* biases   = (const float*)d_in[5];
    float* out = (float*)d_out;

    char* ws = (char*)d_ws;
    unsigned short* iw_bf  = (unsigned short*)(ws);                  //  3,145,728 B
    unsigned short* connw  = (unsigned short*)(ws + 3145728);        //    524,288 B
    unsigned short* act_a  = (unsigned short*)(ws + 3670016);        //  8,388,608 B
    unsigned short* act_b  = (unsigned short*)(ws + 12058624);       //  8,388,608 B
    float* feat_norm = (float*)(ws + 20447232);                      //    131,072 B
    float* pos_c     = (float*)(ws + 20578304);                      //      8,192 B
    float* inw       = (float*)(ws + 20586496);                      //      2,048 B
    float* biasp     = (float*)(ws + 20588544);                      //      2,048 B
    float* wout      = (float*)(ws + 20590592);                      //     20,480 B

    prep1<<<1, 512, 0, stream>>>(pos, feats, out_w, biases, feat_norm, pos_c, inw, biasp, wout);
    prep2<<<512, 128, 0, stream>>>(pos_c, feat_norm, connw);
    cast_pad<<<512, 256, 0, stream>>>(in_w, iw_bf, 393216L, 384000L);

    gemm1<<<512, 256, 0, stream>>>(x, iw_bf, act_a, inw, biasp);
    gemm2<<<512, 256, 0, stream>>>(act_a, connw, act_b, act_a);
    gemm2<<<512, 256, 0, stream>>>(act_b, connw, act_a, act_b);
    gemm2<<<512, 256, 0, stream>>>(act_a, connw, act_b, act_a);

    out_gemm<<<NBATCH/4, 256, 0, stream>>>(act_b, wout, out);
}

// Round 4
// 127.243 us; speedup vs baseline: 1.4542x; 1.0273x over previous
//
#include <hip/hip_runtime.h>
#include <stdint.h>

#define N_REAL 500
#define NPAD   512
#define K_IN   3072
#define NBATCH 8192
#define NOUT   10
#define RADIUS 20.0f
#define VOLF   100.0f

typedef __attribute__((ext_vector_type(8))) __bf16 bf16x8;
typedef __attribute__((ext_vector_type(4))) float  f32x4;
typedef __attribute__((ext_vector_type(4))) unsigned short us4;

__device__ __forceinline__ unsigned short f2bf(float f) {
    unsigned int u = __float_as_uint(f);
    u += 0x7FFFu + ((u >> 16) & 1u);           // round-to-nearest-even
    return (unsigned short)(u >> 16);
}
__device__ __forceinline__ float bf2f(unsigned short h) {
    return __uint_as_float(((unsigned int)h) << 16);
}
// HW packed f32->bf16 (RNE), 2 insts per float4
__device__ __forceinline__ uint2 cvt_pk4(float4 v) {
    uint2 r;
    asm("v_cvt_pk_bf16_f32 %0, %1, %2" : "=v"(r.x) : "v"(v.x), "v"(v.y));
    asm("v_cvt_pk_bf16_f32 %0, %1, %2" : "=v"(r.y) : "v"(v.z), "v"(v.w));
    return r;
}

#define GLOBAL_AS __attribute__((address_space(1)))
#define LDS_AS    __attribute__((address_space(3)))
__device__ __forceinline__ void glds16(const void* g, void* l) {
    __builtin_amdgcn_global_load_lds((const GLOBAL_AS void*)g, (LDS_AS void*)l, 16, 0, 0);
}

// ---------------- prep1 ----------------
__global__ void prep1(const float* __restrict__ positions,
                      const float* __restrict__ features,
                      const float* __restrict__ out_w,
                      const float* __restrict__ biases,
                      float* __restrict__ feat_norm,   // [512][64]
                      float* __restrict__ pos_c,       // [512][4]
                      float* __restrict__ inw,         // [512]
                      float* __restrict__ biasp,       // [512]
                      float* __restrict__ wout)        // [512][10]
{
    int n = threadIdx.x;  // 512 threads, 1 block
    float e_in = 0.f, e_out = 0.f;
    float px = 0.f, py = 0.f, pz = 0.f;
    if (n < N_REAL) {
        px = fminf(fmaxf(positions[n*3+0], 0.1f), VOLF - 0.1f);
        py = fminf(fmaxf(positions[n*3+1], 0.1f), VOLF - 0.1f);
        pz = fminf(fmaxf(positions[n*3+2], 0.1f), VOLF - 0.1f);
        float xn = px / VOLF;
        e_in  = expf(-2.f * xn);
        e_out = expf(2.f * (xn - 1.f));
        float ss = 0.f;
        for (int f = 0; f < 64; ++f) { float v = features[n*64+f]; ss += v*v; }
        float nm = fmaxf(sqrtf(ss), 1e-6f);
        for (int f = 0; f < 64; ++f) feat_norm[n*64+f] = features[n*64+f] / nm;
    } else {
        for (int f = 0; f < 64; ++f) feat_norm[n*64+f] = 0.f;
    }
    pos_c[n*4+0] = px; pos_c[n*4+1] = py; pos_c[n*4+2] = pz; pos_c[n*4+3] = 0.f;

    __shared__ float s_in[512], s_out[512];
    s_in[n] = e_in; s_out[n] = e_out;
    __syncthreads();
    for (int s = 256; s > 0; s >>= 1) {
        if (n < s) { s_in[n] += s_in[n+s]; s_out[n] += s_out[n+s]; }
        __syncthreads();
    }
    float sum_in  = s_in[0]  + 1e-6f;
    float sum_out = s_out[0] + 1e-6f;

    inw[n]   = (n < N_REAL) ? (e_in / sum_in) : 0.f;
    biasp[n] = (n < N_REAL) ? biases[n] : 0.f;
    float wo = (n < N_REAL) ? (e_out / sum_out) : 0.f;
    for (int o = 0; o < NOUT; ++o)
        wout[n*NOUT + o] = (n < N_REAL) ? out_w[n*NOUT + o] * wo : 0.f;
}

// ---------------- prep2 ----------------
__global__ void prep2(const float* __restrict__ pos_c,
                      const float* __restrict__ feat_norm,
                      unsigned short* __restrict__ conn_w)   // [512][512] bf16
{
    int i = blockIdx.x;   // 512
    int t = threadIdx.x;  // 128
    __shared__ float fi[64];
    __shared__ float spos[4];
    __shared__ float red[128];
    if (t < 64) fi[t] = feat_norm[i*64 + t];
    if (t < 4)  spos[t] = pos_c[i*4 + t];
    __syncthreads();

    float w[4];
    float part = 0.f;
    for (int jj = 0; jj < 4; ++jj) {
        int j = t + jj*128;
        float val = 0.f;
        if (i < N_REAL && j < N_REAL) {
            float dx = spos[0] - pos_c[j*4+0];
            float dy = spos[1] - pos_c[j*4+1];
            float dz = spos[2] - pos_c[j*4+2];
            float sq = dx*dx + dy*dy + dz*dz;
            if (sq > 0.f) {
                float dist = sqrtf(sq);
                if (dist < RADIUS) {
                    float att = expf(-dist / RADIUS);
                    float sim = 0.f;
                    const float4* fj = (const float4*)(feat_norm + j*64);
                    const float4* fi4 = (const float4*)fi;
                    #pragma unroll
                    for (int f = 0; f < 16; ++f) {
                        float4 a = fi4[f]; float4 b = fj[f];
                        sim += a.x*b.x + a.y*b.y + a.z*b.z + a.w*b.w;
                    }
                    sim = fminf(fmaxf(sim, -1.f), 1.f);
                    val = att * (0.5f + 0.5f*sim);
                }
            }
        }
        w[jj] = val; part += val;
    }
    red[t] = part;
    __syncthreads();
    for (int s = 64; s > 0; s >>= 1) {
        if (t < s) red[t] += red[t+s];
        __syncthreads();
    }
    float inv = 1.f / (red[0] + 1e-6f);
    for (int jj = 0; jj < 4; ++jj)
        conn_w[(long)i*NPAD + t + jj*128] = f2bf(w[jj] * inv);
}

// ---------------- cast/pad f32 -> bf16 ----------------
__global__ void cast_pad(const float* __restrict__ src, unsigned short* __restrict__ dst,
                         long total_q, long src_q)
{
    long i = (long)blockIdx.x * blockDim.x + threadIdx.x;
    long stride = (long)gridDim.x * blockDim.x;
    for (; i < total_q; i += stride) {
        us4 o;
        if (i < src_q) {
            float4 v = ((const float4*)src)[i];
            o[0] = f2bf(v.x); o[1] = f2bf(v.y); o[2] = f2bf(v.z); o[3] = f2bf(v.w);
        } else {
            o[0] = 0; o[1] = 0; o[2] = 0; o[3] = 0;
        }
        ((us4*)dst)[i] = o;
    }
}

// XCD-grouped block mapping: 1024 blocks = 128 mb x 8 nb; each XCD owns 16 mb,
// nb fastest so the A row-panel stays hot in that XCD's L2.
__device__ __forceinline__ void block_map(int b, int& m0, int& n0) {
    int xcd = b & 7, loc = b >> 3;          // loc 0..127
    m0 = (xcd*16 + (loc >> 3)) * 64;
    n0 = (loc & 7) * 64;
}

// ---------------- GEMM1: act = (x @ iw^T) * inw + bias, fused cast ----------------
// Tile 64x64, BK=64, 4 waves (2x2, each 32x32). Strict single-buffer loop.
__global__ __launch_bounds__(256)
void gemm1(const float* __restrict__ X,            // [8192][3072] f32
           const unsigned short* __restrict__ B,   // [512][3072] bf16
           unsigned short* __restrict__ Cbf,       // [8192][512] bf16
           const float* __restrict__ inw,
           const float* __restrict__ biasp)
{
    __shared__ unsigned short As[64*64];  // 8 KiB, swizzled
    __shared__ unsigned short Bs[64*64];  // 8 KiB, swizzled

    const int tid  = threadIdx.x;
    const int lane = tid & 63;
    const int wave = tid >> 6;
    int m0, n0; block_map(blockIdx.x, m0, n0);
    const int wm = (wave >> 1) * 32;
    const int wn = (wave & 1) * 32;

    f32x4 acc[2][2];
    #pragma unroll
    for (int i = 0; i < 2; ++i)
        #pragma unroll
        for (int j = 0; j < 2; ++j)
            acc[i][j] = (f32x4){0.f,0.f,0.f,0.f};

    // A reg-staging: 64 rows x 16 float4, 4 per thread
    const float4* gA[4]; int lAo[4];
    #pragma unroll
    for (int s = 0; s < 4; ++s) {
        int f = tid + s*256;
        int row = f >> 4, c4 = f & 15;
        gA[s] = (const float4*)(X + (long)(m0 + row) * K_IN) + c4;
        lAo[s] = row*128 + ((c4*8) ^ ((row & 7) << 4));
    }
    // B: 2 glds16 issues, pre-swizzled global source
    const char* gB[2]; char* lB[2];
    #pragma unroll
    for (int s = 0; s < 2; ++s) {
        int o = tid*16 + s*4096;
        int row = o >> 7, d = o & 127;
        gB[s] = (const char*)B + (long)(n0 + row) * (K_IN*2) + (d ^ ((row & 7) << 4));
        lB[s] = (char*)Bs + o;
    }

    for (int t = 0; t < 48; ++t) {
        __syncthreads();
        glds16(gB[0], lB[0]);
        glds16(gB[1], lB[1]);
        gB[0] += 128; gB[1] += 128;
        float4 v[4];
        #pragma unroll
        for (int s = 0; s < 4; ++s) { v[s] = gA[s][0]; gA[s] += 16; }
        #pragma unroll
        for (int s = 0; s < 4; ++s)
            *(uint2*)((char*)As + lAo[s]) = cvt_pk4(v[s]);
        asm volatile("s_waitcnt vmcnt(0) lgkmcnt(0)" ::: "memory");
        __syncthreads();

        #pragma unroll
        for (int kk = 0; kk < 2; ++kk) {
            const int cb = kk*64 + (lane >> 4) * 16;
            bf16x8 afr[2], bfr[2];
            #pragma unroll
            for (int i = 0; i < 2; ++i) {
                int r = wm + i*16 + (lane & 15);
                afr[i] = *(const bf16x8*)((const char*)As + r*128 + (cb ^ ((r & 7) << 4)));
            }
            #pragma unroll
            for (int j = 0; j < 2; ++j) {
                int r = wn + j*16 + (lane & 15);
                bfr[j] = *(const bf16x8*)((const char*)Bs + r*128 + (cb ^ ((r & 7) << 4)));
            }
            #pragma unroll
            for (int i = 0; i < 2; ++i)
                #pragma unroll
                for (int j = 0; j < 2; ++j)
                    acc[i][j] = __builtin_amdgcn_mfma_f32_16x16x32_bf16(afr[i], bfr[j], acc[i][j], 0, 0, 0);
        }
    }

    const int mbase = m0 + wm + (lane >> 4) * 4;
    const int nbase = n0 + wn + (lane & 15);
    #pragma unroll
    for (int j = 0; j < 2; ++j) {
        const int n = nbase + j*16;
        const float win = inw[n], bia = biasp[n];
        #pragma unroll
        for (int i = 0; i < 2; ++i)
            #pragma unroll
            for (int r = 0; r < 4; ++r) {
                const long m = mbase + i*16 + r;
                Cbf[m*NPAD + n] = f2bf(acc[i][j][r] * win + bia);
            }
    }
}

// ---------------- GEMM2: act' = min(relu(act + 0.5 * act @ connw^T), 50) ----------------
__global__ __launch_bounds__(256)
void gemm2(const unsigned short* __restrict__ A,      // act [8192][512] bf16
           const unsigned short* __restrict__ B,      // connw [512][512] bf16
           unsigned short* __restrict__ Cbf,          // [8192][512] bf16
           const unsigned short* __restrict__ actOld) // == A
{
    __shared__ unsigned short As[64*64];
    __shared__ unsigned short Bs[64*64];

    const int tid  = threadIdx.x;
    const int lane = tid & 63;
    const int wave = tid >> 6;
    int m0, n0; block_map(blockIdx.x, m0, n0);
    const int wm = (wave >> 1) * 32;
    const int wn = (wave & 1) * 32;

    f32x4 acc[2][2];
    #pragma unroll
    for (int i = 0; i < 2; ++i)
        #pragma unroll
        for (int j = 0; j < 2; ++j)
            acc[i][j] = (f32x4){0.f,0.f,0.f,0.f};

    const char* gA[2]; char* lA[2];
    #pragma unroll
    for (int s = 0; s < 2; ++s) {
        int o = tid*16 + s*4096;
        int row = o >> 7, d = o & 127;
        gA[s] = (const char*)A + (long)(m0 + row) * (NPAD*2) + (d ^ ((row & 7) << 4));
        lA[s] = (char*)As + o;
    }
    const char* gB[2]; char* lB[2];
    #pragma unroll
    for (int s = 0; s < 2; ++s) {
        int o = tid*16 + s*4096;
        int row = o >> 7, d = o & 127;
        gB[s] = (const char*)B + (long)(n0 + row) * (NPAD*2) + (d ^ ((row & 7) << 4));
        lB[s] = (char*)Bs + o;
    }

    // pre-issue epilogue actOld loads (hidden under K-loop)
    const int mbase = m0 + wm + (lane >> 4) * 4;
    const int nbase = n0 + wn + (lane & 15);
    unsigned short oldv[2][8];
    #pragma unroll
    for (int j = 0; j < 2; ++j)
        #pragma unroll
        for (int i = 0; i < 2; ++i)
            #pragma unroll
            for (int r = 0; r < 4; ++r)
                oldv[j][i*4+r] = actOld[(long)(mbase + i*16 + r)*NPAD + nbase + j*16];

    for (int t = 0; t < 8; ++t) {
        __syncthreads();
        #pragma unroll
        for (int s = 0; s < 2; ++s) { glds16(gA[s], lA[s]); gA[s] += 128; }
        #pragma unroll
        for (int s = 0; s < 2; ++s) { glds16(gB[s], lB[s]); gB[s] += 128; }
        asm volatile("s_waitcnt vmcnt(0)" ::: "memory");
        __syncthreads();

        #pragma unroll
        for (int kk = 0; kk < 2; ++kk) {
            const int cb = kk*64 + (lane >> 4) * 16;
            bf16x8 afr[2], bfr[2];
            #pragma unroll
            for (int i = 0; i < 2; ++i) {
                int r = wm + i*16 + (lane & 15);
                afr[i] = *(const bf16x8*)((const char*)As + r*128 + (cb ^ ((r & 7) << 4)));
            }
            #pragma unroll
            for (int j = 0; j < 2; ++j) {
                int r = wn + j*16 + (lane & 15);
                bfr[j] = *(const bf16x8*)((const char*)Bs + r*128 + (cb ^ ((r & 7) << 4)));
            }
            #pragma unroll
            for (int i = 0; i < 2; ++i)
                #pragma unroll
                for (int j = 0; j < 2; ++j)
                    acc[i][j] = __builtin_amdgcn_mfma_f32_16x16x32_bf16(afr[i], bfr[j], acc[i][j], 0, 0, 0);
        }
    }

    #pragma unroll
    for (int j = 0; j < 2; ++j) {
        const int n = nbase + j*16;
        #pragma unroll
        for (int i = 0; i < 2; ++i)
            #pragma unroll
            for (int r = 0; r < 4; ++r) {
                const long m = mbase + i*16 + r;
                float old = bf2f(oldv[j][i*4+r]);
                float vv = fminf(fmaxf(old + 0.5f * acc[i][j][r], 0.f), 50.f);
                Cbf[m*NPAD + n] = f2bf(vv);
            }
    }
}

// ---------------- final projection: out[8192][10] = act @ wout ----------------
__global__ __launch_bounds__(256)
void out_gemm(const unsigned short* __restrict__ act,  // [8192][512] bf16
              const float* __restrict__ wout,          // [512][10]
              float* __restrict__ out)                 // [8192][10]
{
    __shared__ float sw[NPAD * NOUT];
    const int tid = threadIdx.x;
    for (int i = tid; i < NPAD*NOUT; i += 256) sw[i] = wout[i];
    __syncthreads();

    const int lane = tid & 63;
    const int wv   = tid >> 6;
    const int row  = blockIdx.x * 4 + wv;

    const unsigned short* ap = act + (long)row * NPAD + lane * 8;
    us4 v0 = *(const us4*)(ap);
    us4 v1 = *(const us4*)(ap + 4);

    float p[NOUT];
    #pragma unroll
    for (int o = 0; o < NOUT; ++o) p[o] = 0.f;

    const int nb = lane * 8;
    #pragma unroll
    for (int e = 0; e < 8; ++e) {
        float a = bf2f(e < 4 ? v0[e] : v1[e-4]);
        const float* wr = &sw[(nb + e) * NOUT];
        #pragma unroll
        for (int o = 0; o < NOUT; ++o) p[o] += a * wr[o];
    }
    #pragma unroll
    for (int o = 0; o < NOUT; ++o) {
        float s = p[o];
        for (int d = 32; d > 0; d >>= 1) s += __shfl_down(s, d);
        if (lane == 0) out[(long)row * NOUT + o] = s;
    }
}

extern "C" void kernel_launch(void* const* d_in, const int* in_sizes, int n_in,
                              void* d_out, int out_size, void* d_ws, size_t ws_size,
                              hipStream_t stream)
{
    const float* x        = (const float*)d_in[0];
    const float* pos      = (const float*)d_in[1];
    const float* in_w     = (const float*)d_in[2];
    const float* feats    = (const float*)d_in[3];
    const float* out_w    = (const float*)d_in[4];
    const float* biases   = (const float*)d_in[5];
    float* out = (float*)d_out;

    char* ws = (char*)d_ws;
    unsigned short* iw_bf  = (unsigned short*)(ws);                  //  3,145,728 B
    unsigned short* connw  = (unsigned short*)(ws + 3145728);        //    524,288 B
    unsigned short* act_a  = (unsigned short*)(ws + 3670016);        //  8,388,608 B
    unsigned short* act_b  = (unsigned short*)(ws + 12058624);       //  8,388,608 B
    float* feat_norm = (float*)(ws + 20447232);                      //    131,072 B
    float* pos_c     = (float*)(ws + 20578304);                      //      8,192 B
    float* inw       = (float*)(ws + 20586496);                      //      2,048 B
    float* biasp     = (float*)(ws + 20588544);                      //      2,048 B
    float* wout      = (float*)(ws + 20590592);                      //     20,480 B

    prep1<<<1, 512, 0, stream>>>(pos, feats, out_w, biases, feat_norm, pos_c, inw, biasp, wout);
    prep2<<<512, 128, 0, stream>>>(pos_c, feat_norm, connw);
    cast_pad<<<512, 256, 0, stream>>>(in_w, iw_bf, 393216L, 384000L);

    gemm1<<<1024, 256, 0, stream>>>(x, iw_bf, act_a, inw, biasp);
    gemm2<<<1024, 256, 0, stream>>>(act_a, connw, act_b, act_a);
    gemm2<<<1024, 256, 0, stream>>>(act_b, connw, act_a, act_b);
    gemm2<<<1024, 256, 0, stream>>>(act_a, connw, act_b, act_a);

    out_gemm<<<NBATCH/4, 256, 0, stream>>>(act_b, wout, out);
}